// Round 15
// baseline (1537.477 us; speedup 1.0000x reference)
//
#include <hip/hip_runtime.h>
#include <math.h>

#define VNUM 50000
#define OUTF 128
#define NEDGE 1600000
#define EPSF 1e-7f

#define CONV_BLOCKS 12500   // 50000 rows / 4 rows per block
#define BFRAG_BLOCKS 64     // 16384 uint pairs / 256

#define CHUNK 2048          // edges per coarse block
#define NCB 196             // coarse bins: tidx>>8 (256 vertices/bin)
#define COARSE_BLOCKS 782   // ceil(NEDGE/CHUNK)
#define BSTRIDE 10240       // fixed coarse8 segment stride; mean 8192 + 22.7 sigma
#define AGG_UNROLL 12

typedef __attribute__((ext_vector_type(8))) short short8;
typedef __attribute__((ext_vector_type(4))) float v4f;

// ---------------------------------------------------------------------------
// bf16 helpers (RNE)
// ---------------------------------------------------------------------------
__device__ __forceinline__ unsigned short f2bf(float f) {
    union { float f; unsigned int u; } c; c.f = f;
    unsigned int u = c.u;
    return (unsigned short)((u + 0x7FFFu + ((u >> 16) & 1u)) >> 16);
}
__device__ __forceinline__ float bf16_lo(unsigned int p) {
    union { unsigned int u; float f; } c; c.u = p << 16; return c.f;
}
__device__ __forceinline__ float bf16_hi(unsigned int p) {
    union { unsigned int u; float f; } c; c.u = p & 0xFFFF0000u; return c.f;
}

__device__ __forceinline__ int wave_incl_scan(int v, int lane) {
#pragma unroll
    for (int off = 1; off < 64; off <<= 1) {
        const int o = __shfl_up(v, off, 64);
        if (lane >= off) v += o;
    }
    return v;
}

// ---------------------------------------------------------------------------
// prep: (a) vrepr f32 -> bf16x2 INTERLEAVED in the loc half: row v's pack
// lives at out_u32[v*128+64 .. v*128+128), cols (l, l+64) per uint (swizzled
// so aggregate_fused's two ds_adds are unit-lane-stride = conflict-free).
// accu16 will occupy out_u32[v*128 .. v*128+64) — byte-disjoint. (b) ccursor
// init (fixed-stride bins). (c) MFMA B-fragment build.
// ---------------------------------------------------------------------------
__global__ __launch_bounds__(256) void prep_kernel(
    const float* __restrict__ vrepr, unsigned int* __restrict__ outu,
    int* __restrict__ ccursor,
    const float* __restrict__ loc_w, const float* __restrict__ std_w,
    unsigned int* bfrag)
{
    const int b = blockIdx.x, tid = threadIdx.x;
    if (b < CONV_BLOCKS) {
        const int r = b * 4 + (tid >> 6), l = tid & 63;
        const float lo = vrepr[(size_t)r * 128 + l];
        const float hi = vrepr[(size_t)r * 128 + l + 64];
        outu[(size_t)r * 128 + 64 + l] =
            (unsigned)f2bf(lo) | ((unsigned)f2bf(hi) << 16);
    } else if (b == CONV_BLOCKS) {
        if (tid < NCB) ccursor[tid] = tid * BSTRIDE;
    } else {
        const int p = (b - (CONV_BLOCKS + 1)) * 256 + tid; // 0..16383
        const int j2 = p & 3, lq = (p >> 2) & 63, ks = (p >> 8) & 3, ct = p >> 10;
        const int k = ks * 32 + (lq >> 4) * 8 + j2 * 2;
        const int n = ct * 16 + (lq & 15);
        const float* wsrc = (n >> 7) ? std_w : loc_w;
        const int c = n & 127;
        bfrag[p] = (unsigned)f2bf(wsrc[c * 128 + k]) |
                   ((unsigned)f2bf(wsrc[c * 128 + k + 1]) << 16);
    }
}

// ---------------------------------------------------------------------------
// coarse: partition edges into 196 fixed-stride bin segments (256 verts/bin)
// via LDS staging + bulk-reserved contiguous runs. rec={sidx<<16|bf16(w),tidx}
// 256-thread block scan over 196 bins (4 waves + wsum combine).
// ---------------------------------------------------------------------------
__global__ __launch_bounds__(256) void coarse_kernel(
    const int* __restrict__ sidx, const int* __restrict__ tidx,
    const float* __restrict__ enorm, const float* __restrict__ esgn,
    int* __restrict__ ccursor, uint2* __restrict__ coarse8)
{
    __shared__ uint2 lrec[CHUNK];      // 16 KB
    __shared__ int lcnt[4][NCB];
    __shared__ int lbase[4][NCB];
    __shared__ int loffs[NCB];
    __shared__ int grun[NCB];
    __shared__ int wsum[4];

    const int tid = threadIdx.x, lane = tid & 63, wv = tid >> 6;
    const int base = blockIdx.x * CHUNK;
    const int n = min(CHUNK, NEDGE - base);

    for (int i = tid; i < 4 * NCB; i += 256) (&lcnt[0][0])[i] = 0;
    __syncthreads();

    uint2 rec[8];
#pragma unroll
    for (int j = 0; j < 8; ++j) {
        const int e = base + j * 256 + tid;
        if (e < NEDGE) {
            const int t = tidx[e];
            const float w = esgn[e] * enorm[e];
            rec[j].x = ((unsigned)sidx[e] << 16) | (unsigned)f2bf(w);
            rec[j].y = (unsigned)t;
            atomicAdd(&lcnt[wv][t >> 8], 1);
        }
    }
    __syncthreads();

    {
        int c0 = 0, c1 = 0, c2 = 0, c3 = 0, tot = 0;
        if (tid < NCB) {
            c0 = lcnt[0][tid]; c1 = lcnt[1][tid];
            c2 = lcnt[2][tid]; c3 = lcnt[3][tid];
            tot = c0 + c1 + c2 + c3;
        }
        const int inc = wave_incl_scan(tot, lane);
        if (lane == 63) wsum[wv] = inc;
        __syncthreads();
        if (tid == 0) {
            int run = 0;
#pragma unroll
            for (int i = 0; i < 4; ++i) { const int t2 = wsum[i]; wsum[i] = run; run += t2; }
        }
        __syncthreads();
        const int ex = wsum[wv] + inc - tot;
        if (tid < NCB) {
            loffs[tid]    = ex;
            lbase[0][tid] = ex;
            lbase[1][tid] = ex + c0;
            lbase[2][tid] = ex + c0 + c1;
            lbase[3][tid] = ex + c0 + c1 + c2;
            grun[tid] = atomicAdd(&ccursor[tid], tot);
        }
    }
    __syncthreads();

#pragma unroll
    for (int j = 0; j < 8; ++j) {
        const int e = base + j * 256 + tid;
        if (e < NEDGE) {
            const int cb = (int)(rec[j].y >> 8);
            const int pos = atomicAdd(&lbase[wv][cb], 1);
            lrec[pos] = rec[j];
        }
    }
    __syncthreads();

    for (int i = tid; i < n; i += 256) {
        const uint2 r = lrec[i];
        const int cb = (int)(r.y >> 8);
        coarse8[grun[cb] + (i - loffs[cb])] = r;
    }
}

// ---------------------------------------------------------------------------
// aggregate_fused (R12): replaces hist + scatter_fine + aggregate. One block
// per 256-vertex bin; LDS accumulator [256][128] f32 (128 KB). Streams the
// bin's coarse8 segment ONCE (NT), per record: broadcast rec, 256 B row
// gather from interleaved vrepr16, per-lane 2x ds_add_f32 (cols l, l+64 —
// unit lane stride, 2-way bank = free). Final: repack to (2j,2j+1) uints
// (gemm's expected accu16 layout) and store to loc even-chunks.
// Order-insensitive f32 sum — segment_sum doesn't need sorted pairs.
// ---------------------------------------------------------------------------
__global__ __launch_bounds__(1024) void aggregate_fused_kernel(
    const uint2* __restrict__ coarse8, const int* __restrict__ ccursor,
    unsigned int* __restrict__ outu)
{
    __shared__ float acc[256][128];    // 128 KB
    const int tid = threadIdx.x, lane = tid & 63, wv = tid >> 6;  // 16 waves
    const int bin = blockIdx.x;
    const int seg0 = bin * BSTRIDE;
    const int seg1 = ccursor[bin];

    for (int k = tid; k < 256 * 128; k += 1024) (&acc[0][0])[k] = 0.0f;
    __syncthreads();

    int b0 = seg0 + wv * AGG_UNROLL;
    const int stride = 16 * AGG_UNROLL;
    for (; b0 + AGG_UNROLL <= seg1; b0 += stride) {
        unsigned px[AGG_UNROLL], py[AGG_UNROLL], rr[AGG_UNROLL];
#pragma unroll
        for (int j = 0; j < AGG_UNROLL; ++j) {
            px[j] = __builtin_nontemporal_load(&coarse8[b0 + j].x);
            py[j] = __builtin_nontemporal_load(&coarse8[b0 + j].y);
        }
#pragma unroll
        for (int j = 0; j < AGG_UNROLL; ++j)
            rr[j] = outu[(size_t)(px[j] >> 16) * 128 + 64 + lane];
#pragma unroll
        for (int j = 0; j < AGG_UNROLL; ++j) {
            const float w = bf16_lo(px[j]);
            const int vl = (int)(py[j] & 255);
            atomicAdd(&acc[vl][lane],      bf16_lo(rr[j]) * w);
            atomicAdd(&acc[vl][lane + 64], bf16_hi(rr[j]) * w);
        }
    }
    for (int i = b0; i < seg1 && i < b0 + AGG_UNROLL; ++i) {
        const unsigned px = coarse8[i].x, py = coarse8[i].y;
        const unsigned rr = outu[(size_t)(px >> 16) * 128 + 64 + lane];
        const float w = bf16_lo(px);
        const int vl = (int)(py & 255);
        atomicAdd(&acc[vl][lane],      bf16_lo(rr) * w);
        atomicAdd(&acc[vl][lane + 64], bf16_hi(rr) * w);
    }
    __syncthreads();

    const int vbase = bin << 8;
    for (int u = tid; u < 256 * 64; u += 1024) {
        const int vl = u >> 6, j = u & 63;
        if (vbase + vl < VNUM) {
            const unsigned pk = (unsigned)f2bf(acc[vl][2 * j]) |
                                ((unsigned)f2bf(acc[vl][2 * j + 1]) << 16);
            outu[(size_t)(vbase + vl) * 128 + j] = pk;
        }
    }
}

// ---------------------------------------------------------------------------
// gemm via MFMA 16x16x32 bf16. A-tile read pre-packed bf16 accu16 at
// out_u32[row*128 .. row*128+64). In-place safe: block reads exactly the
// even-chunks of the rows it overwrites (vrepr16 odd-chunks dead by now).
// ---------------------------------------------------------------------------
__global__ __launch_bounds__(256) void gemm_mfma_kernel(
    const unsigned int* accu, const unsigned int* __restrict__ bfrag,
    const float* __restrict__ loc_b, const float* __restrict__ std_b,
    float* out)
{
    __shared__ unsigned short tile[16][136];   // bf16, padded
    const int t = threadIdx.x;
    const int row0 = blockIdx.x * 16;
    const int l = t & 63, w = t >> 6;

    short8 bfr[4][4];
#pragma unroll
    for (int ct = 0; ct < 4; ++ct)
#pragma unroll
        for (int ks = 0; ks < 4; ++ks)
            bfr[ct][ks] = *reinterpret_cast<const short8*>(
                bfrag + ((((w * 4 + ct) * 4 + ks) * 64 + l) << 2));

    {
        const uint4 av = *reinterpret_cast<const uint4*>(
            accu + (size_t)(row0 + (t >> 4)) * 128 + (t & 15) * 4);
        *reinterpret_cast<uint4*>(&tile[t >> 4][(t & 15) * 8]) = av;
    }
    __syncthreads();

    const int m = l & 15, q = l >> 4;
    v4f accv[4];
#pragma unroll
    for (int ct = 0; ct < 4; ++ct) accv[ct] = (v4f){0.0f, 0.0f, 0.0f, 0.0f};

#pragma unroll
    for (int ks = 0; ks < 4; ++ks) {
        const short8 a = *reinterpret_cast<const short8*>(&tile[m][ks * 32 + q * 8]);
#pragma unroll
        for (int ct = 0; ct < 4; ++ct)
            accv[ct] = __builtin_amdgcn_mfma_f32_16x16x32_bf16(
                a, bfr[ct][ks], accv[ct], 0, 0, 0);
    }

#pragma unroll
    for (int ct = 0; ct < 4; ++ct) {
        const int colg = (w * 4 + ct) * 16 + m;
        const int h = colg >> 7, c = colg & 127;
        const float bias = (h ? std_b : loc_b)[c];
        float* dst = out + (h ? (size_t)VNUM * OUTF : (size_t)0);
#pragma unroll
        for (int reg = 0; reg < 4; ++reg) {
            const int row = row0 + q * 4 + reg;
            float x = accv[ct][reg] + bias;
            if (h) x = fmaxf(x, 0.0f) + log1pf(expf(-fabsf(x))) + EPSF;
            dst[(size_t)row * OUTF + c] = x;
        }
    }
}

// Fallback gemm (no workspace): f32 vector path, unpacks bf16 acc.
__global__ __launch_bounds__(256) void gemm_fallback_kernel(
    const unsigned int* accu,
    const float* __restrict__ loc_w, const float* __restrict__ loc_b,
    const float* __restrict__ std_w, const float* __restrict__ std_b,
    float* out)
{
    __shared__ float tile[16][OUTF];
    const int t = threadIdx.x;
    const int row0 = blockIdx.x * 16;
    {
        const uint4 av = *reinterpret_cast<const uint4*>(
            accu + (size_t)(row0 + (t >> 4)) * 128 + (t & 15) * 4);
        float* dst = &tile[t >> 4][(t & 15) * 8];
        dst[0] = bf16_lo(av.x); dst[1] = bf16_hi(av.x);
        dst[2] = bf16_lo(av.y); dst[3] = bf16_hi(av.y);
        dst[4] = bf16_lo(av.z); dst[5] = bf16_hi(av.z);
        dst[6] = bf16_lo(av.w); dst[7] = bf16_hi(av.w);
    }
    __syncthreads();
    const int is_std = t >> 7;
    const int c = t & 127;
    const float* w = (is_std ? std_w : loc_w) + (size_t)c * OUTF;
    const float bias = is_std ? std_b[c] : loc_b[c];
    float accv[16];
#pragma unroll
    for (int r = 0; r < 16; ++r) accv[r] = 0.0f;
    for (int k = 0; k < OUTF; k += 4) {
        const float4 wv = *reinterpret_cast<const float4*>(w + k);
#pragma unroll
        for (int r = 0; r < 16; ++r) {
            const float4 pv = *reinterpret_cast<const float4*>(&tile[r][k]);
            float a = accv[r];
            a = fmaf(pv.x, wv.x, a); a = fmaf(pv.y, wv.y, a);
            a = fmaf(pv.z, wv.z, a); a = fmaf(pv.w, wv.w, a);
            accv[r] = a;
        }
    }
    float* dst_base = out + (is_std ? (size_t)VNUM * OUTF : (size_t)0);
#pragma unroll
    for (int r = 0; r < 16; ++r) {
        const float x = accv[r] + bias;
        dst_base[(size_t)(row0 + r) * OUTF + c] =
            is_std ? (fmaxf(x, 0.0f) + log1pf(expf(-fabsf(x))) + EPSF) : x;
    }
}

extern "C" void kernel_launch(void* const* d_in, const int* in_sizes, int n_in,
                              void* d_out, int out_size, void* d_ws, size_t ws_size,
                              hipStream_t stream) {
    const int*   sidx  = (const int*)  d_in[0];
    const int*   tidx  = (const int*)  d_in[1];
    const float* enorm = (const float*)d_in[2];
    const float* esgn  = (const float*)d_in[3];
    const float* vrepr = (const float*)d_in[4];
    const float* loc_w = (const float*)d_in[5];
    const float* loc_b = (const float*)d_in[6];
    const float* std_w = (const float*)d_in[7];
    const float* std_b = (const float*)d_in[8];

    float* out = (float*)d_out;

    // Loc half (6.4M uints): row v's 512 B = [accu16 pack 256B | vrepr16 pack
    // 256B] — prep fills odd chunks, aggregate_fused reads odd / writes even,
    // gemm reads even and overwrites rows in place (identity mapping).
    unsigned int* outu = (unsigned int*)out;

    // Std half: coarse8 (196*10240 recs = 16.06 MB) | ccursor 196
    unsigned int* sbase = (unsigned int*)(out + (size_t)VNUM * OUTF);
    uint2* coarse8 = (uint2*)sbase;
    int* ccursor = (int*)(sbase + (size_t)2 * NCB * BSTRIDE);

    const bool use_ws = ws_size >= 16384 * sizeof(unsigned int);  // 64 KB
    unsigned int* bfrag = use_ws ? (unsigned int*)d_ws : nullptr;

    const int prep_blocks = CONV_BLOCKS + 1 + (use_ws ? BFRAG_BLOCKS : 0);
    prep_kernel           <<<prep_blocks, 256, 0, stream>>>(vrepr, outu, ccursor,
                                                            loc_w, std_w, bfrag);
    coarse_kernel         <<<COARSE_BLOCKS, 256, 0, stream>>>(sidx, tidx, enorm,
                                                              esgn, ccursor, coarse8);
    aggregate_fused_kernel<<<NCB, 1024, 0, stream>>>(coarse8, ccursor, outu);

    if (use_ws) {
        gemm_mfma_kernel<<<VNUM / 16, 256, 0, stream>>>(outu, bfrag, loc_b, std_b, out);
    } else {
        gemm_fallback_kernel<<<VNUM / 16, 256, 0, stream>>>(outu, loc_w, loc_b,
                                                            std_w, std_b, out);
    }
}

// Round 17
// 228.579 us; speedup vs baseline: 6.7262x; 6.7262x over previous
//
#include <hip/hip_runtime.h>
#include <math.h>

#define VNUM 50000
#define OUTF 128
#define NEDGE 1600000
#define EPSF 1e-7f

#define CONV_BLOCKS 6250    // 50000*128 / (256*4)
#define BFRAG_BLOCKS 64     // 16384 uint pairs / 256

#define CHUNK 2048          // edges per coarse block
#define NCB 49              // coarse bins: tidx>>10 (1024 vertices/bin)
#define COARSE_BLOCKS 782   // ceil(NEDGE/CHUNK)
#define BSTRIDE 36864       // fixed coarse8 segment stride; mean 32768 + 23 sigma
#define NSUB 4              // sub-blocks per bin (R8: 8 = +6.5us; R10 coop = +35us; R15 LDS-fuse = +1300us)
#define FINE_BLOCKS (NCB * NSUB)   // 196

typedef __attribute__((ext_vector_type(8))) short short8;
typedef __attribute__((ext_vector_type(4))) float v4f;

// ---------------------------------------------------------------------------
// bf16 helpers (RNE)
// ---------------------------------------------------------------------------
__device__ __forceinline__ unsigned short f2bf(float f) {
    union { float f; unsigned int u; } c; c.f = f;
    unsigned int u = c.u;
    return (unsigned short)((u + 0x7FFFu + ((u >> 16) & 1u)) >> 16);
}
__device__ __forceinline__ float bf16_lo(unsigned int p) {
    union { unsigned int u; float f; } c; c.u = p << 16; return c.f;
}
__device__ __forceinline__ float bf16_hi(unsigned int p) {
    union { unsigned int u; float f; } c; c.u = p & 0xFFFF0000u; return c.f;
}

__device__ __forceinline__ int wave_incl_scan(int v, int lane) {
#pragma unroll
    for (int off = 1; off < 64; off <<= 1) {
        const int o = __shfl_up(v, off, 64);
        if (lane >= off) v += o;
    }
    return v;
}

// ---------------------------------------------------------------------------
// prep: (a) vrepr f32 -> packed bf16x2, (b) ccursor init (fixed-stride bins)
// + offs[VNUM]=NEDGE (constant), (c) MFMA B-fragment build.
// ---------------------------------------------------------------------------
__global__ __launch_bounds__(256) void prep_kernel(
    const float* __restrict__ vrepr, unsigned int* __restrict__ vrepr16,
    int* __restrict__ ccursor, int* __restrict__ offs,
    const float* __restrict__ loc_w, const float* __restrict__ std_w,
    unsigned int* bfrag)
{
    const int b = blockIdx.x, tid = threadIdx.x;
    if (b < CONV_BLOCKS) {
        const size_t base = (size_t)b * 1024 + tid * 4;
        const float4 v = *reinterpret_cast<const float4*>(vrepr + base);
        uint2 o;
        o.x = (unsigned)f2bf(v.x) | ((unsigned)f2bf(v.y) << 16);
        o.y = (unsigned)f2bf(v.z) | ((unsigned)f2bf(v.w) << 16);
        *reinterpret_cast<uint2*>(vrepr16 + base / 2) = o;
    } else if (b == CONV_BLOCKS) {
        if (tid < NCB) ccursor[tid] = tid * BSTRIDE;
        if (tid == 63) offs[VNUM] = NEDGE;
    } else {
        const int p = (b - (CONV_BLOCKS + 1)) * 256 + tid; // 0..16383
        const int j2 = p & 3, lq = (p >> 2) & 63, ks = (p >> 8) & 3, ct = p >> 10;
        const int k = ks * 32 + (lq >> 4) * 8 + j2 * 2;
        const int n = ct * 16 + (lq & 15);
        const float* wsrc = (n >> 7) ? std_w : loc_w;
        const int c = n & 127;
        bfrag[p] = (unsigned)f2bf(wsrc[c * 128 + k]) |
                   ((unsigned)f2bf(wsrc[c * 128 + k + 1]) << 16);
    }
}

// ---------------------------------------------------------------------------
// coarse: partition edges into 49 fixed-stride bin segments via LDS staging
// + bulk-reserved contiguous runs. rec = { sidx<<16 | bf16(w), tidx }
// ---------------------------------------------------------------------------
__global__ __launch_bounds__(256) void coarse_kernel(
    const int* __restrict__ sidx, const int* __restrict__ tidx,
    const float* __restrict__ enorm, const float* __restrict__ esgn,
    int* __restrict__ ccursor, uint2* __restrict__ coarse8)
{
    __shared__ uint2 lrec[CHUNK];      // 16 KB
    __shared__ int lcnt[4][NCB];
    __shared__ int lbase[4][NCB];
    __shared__ int loffs[NCB];
    __shared__ int grun[NCB];

    const int tid = threadIdx.x, lane = tid & 63, wv = tid >> 6;
    const int base = blockIdx.x * CHUNK;
    const int n = min(CHUNK, NEDGE - base);

    for (int i = tid; i < 4 * NCB; i += 256) (&lcnt[0][0])[i] = 0;
    __syncthreads();

    uint2 rec[8];
#pragma unroll
    for (int j = 0; j < 8; ++j) {
        const int e = base + j * 256 + tid;
        if (e < NEDGE) {
            const int t = tidx[e];
            const float w = esgn[e] * enorm[e];
            rec[j].x = ((unsigned)sidx[e] << 16) | (unsigned)f2bf(w);
            rec[j].y = (unsigned)t;
            atomicAdd(&lcnt[wv][t >> 10], 1);
        }
    }
    __syncthreads();

    if (tid < 64) {
        int c0 = 0, c1 = 0, c2 = 0, c3 = 0, tot = 0;
        if (lane < NCB) {
            c0 = lcnt[0][lane]; c1 = lcnt[1][lane];
            c2 = lcnt[2][lane]; c3 = lcnt[3][lane];
            tot = c0 + c1 + c2 + c3;
        }
        const int inc = wave_incl_scan(tot, lane);
        const int ex = inc - tot;
        if (lane < NCB) {
            loffs[lane]    = ex;
            lbase[0][lane] = ex;
            lbase[1][lane] = ex + c0;
            lbase[2][lane] = ex + c0 + c1;
            lbase[3][lane] = ex + c0 + c1 + c2;
            grun[lane] = atomicAdd(&ccursor[lane], tot);
        }
    }
    __syncthreads();

#pragma unroll
    for (int j = 0; j < 8; ++j) {
        const int e = base + j * 256 + tid;
        if (e < NEDGE) {
            const int cb = (int)(rec[j].y >> 10);
            const int pos = atomicAdd(&lbase[wv][cb], 1);
            lrec[pos] = rec[j];
        }
    }
    __syncthreads();

    for (int i = tid; i < n; i += 256) {
        const uint2 r = lrec[i];
        const int cb = (int)(r.y >> 10);
        coarse8[grun[cb] + (i - loffs[cb])] = r;
    }
}

// ---------------------------------------------------------------------------
// hist: 4 sub-blocks per bin; len derived from ccursor. Each histograms
// its quarter into LDS, plain-stores its private 4KB slice.
// ---------------------------------------------------------------------------
__global__ __launch_bounds__(1024) void hist_kernel(
    const uint2* __restrict__ coarse8, const int* __restrict__ ccursor,
    int* __restrict__ hcnt)
{
    __shared__ int cnt[1024];
    const int tid = threadIdx.x;
    const int bin = blockIdx.x >> 2, s = blockIdx.x & 3;
    const int bs = bin * BSTRIDE;
    const int len = ccursor[bin] - bs;
    const int qs = bs + ((len * s) >> 2);
    const int qe = bs + ((len * (s + 1)) >> 2);
    cnt[tid] = 0;
    __syncthreads();
    for (int i = qs + tid; i < qe; i += 1024)
        atomicAdd(&cnt[coarse8[i].y & 1023], 1);
    __syncthreads();
    hcnt[blockIdx.x * 1024 + tid] = cnt[tid];
}

// ---------------------------------------------------------------------------
// scatter_fine: wave 0 recomputes the 49-bin packed prefix from ccursor,
// then bin-wide scan from the 4 hcnt slices, seeds LDS cursors at
// offs[v] + prefix(earlier sub-blocks), ranks + scatters its quarter.
// Sub-range formula identical to hist_kernel -> exact partition.
// ---------------------------------------------------------------------------
__global__ __launch_bounds__(1024) void scatter_fine_kernel(
    const uint2* __restrict__ coarse8, const int* __restrict__ ccursor,
    const int* __restrict__ hcnt, int* __restrict__ offs,
    unsigned int* __restrict__ pairs)
{
    __shared__ int cur[1024];
    __shared__ int wsum[16];
    __shared__ int sh_s0;
    const int tid = threadIdx.x, lane = tid & 63, wv = tid >> 6;
    const int bin = blockIdx.x >> 2, s = blockIdx.x & 3;
    const int bs = bin * BSTRIDE;

    if (tid < 64) {
        const int lenl = (tid < NCB) ? (ccursor[tid] - tid * BSTRIDE) : 0;
        const int incc = wave_incl_scan(lenl, tid);
        if (tid == bin) sh_s0 = incc - lenl;   // packed exclusive prefix
    }

    const int len = ccursor[bin] - bs;
    const int qs = bs + ((len * s) >> 2);
    const int qe = bs + ((len * (s + 1)) >> 2);

    const int c0 = hcnt[(bin * 4 + 0) * 1024 + tid];
    const int c1 = hcnt[(bin * 4 + 1) * 1024 + tid];
    const int c2 = hcnt[(bin * 4 + 2) * 1024 + tid];
    const int c3 = hcnt[(bin * 4 + 3) * 1024 + tid];
    const int tot = c0 + c1 + c2 + c3;
    const int pre = (s > 0 ? c0 : 0) + (s > 1 ? c1 : 0) + (s > 2 ? c2 : 0);

    const int inc = wave_incl_scan(tot, lane);
    if (lane == 63) wsum[wv] = inc;
    __syncthreads();
    if (tid == 0) {
        int run = 0;
        for (int i = 0; i < 16; ++i) { const int t = wsum[i]; wsum[i] = run; run += t; }
    }
    __syncthreads();
    const int ex = sh_s0 + wsum[wv] + inc - tot;   // global offs for vertex gv
    const int gv = (bin << 10) + tid;
    if (s == 0 && gv < VNUM) offs[gv] = ex;
    cur[tid] = ex + pre;
    __syncthreads();

    for (int i = qs + tid; i < qe; i += 1024) {
        const uint2 r = coarse8[i];
        const int pos = atomicAdd(&cur[r.y & 1023], 1);
        pairs[pos] = r.x;
    }
}

// ---------------------------------------------------------------------------
// aggregate: one wave per vertex, lane covers cols (2l, 2l+1). 256 B
// coalesced bf16-row gathers, unroll-12, CACHED pairs loads (R8-proven) +
// nontemporal PACKED-BF16 store (WRITE 25->12.5MB). Same rounding point as
// gemm's old pack -> bit-identical output.
// ---------------------------------------------------------------------------
__global__ __launch_bounds__(256) void aggregate_kernel(
    const int* __restrict__ offs, const unsigned int* __restrict__ pairs,
    const unsigned int* __restrict__ vrepr16, unsigned int* __restrict__ accu)
{
    const int v = blockIdx.x * 4 + (threadIdx.x >> 6);
    const int l = threadIdx.x & 63;
    int i = offs[v];
    const int end = offs[v + 1];

    float a0 = 0.0f, a1 = 0.0f;
    for (; i + 12 <= end; i += 12) {
        unsigned p[12], r[12];
#pragma unroll
        for (int j = 0; j < 12; ++j) p[j] = pairs[i + j];
#pragma unroll
        for (int j = 0; j < 12; ++j) r[j] = vrepr16[(size_t)(p[j] >> 16) * 64 + l];
#pragma unroll
        for (int j = 0; j < 12; ++j) {
            const float w = bf16_lo(p[j]);
            a0 = fmaf(bf16_lo(r[j]), w, a0);
            a1 = fmaf(bf16_hi(r[j]), w, a1);
        }
    }
    for (; i + 4 <= end; i += 4) {
        unsigned p[4], r[4];
#pragma unroll
        for (int j = 0; j < 4; ++j) p[j] = pairs[i + j];
#pragma unroll
        for (int j = 0; j < 4; ++j) r[j] = vrepr16[(size_t)(p[j] >> 16) * 64 + l];
#pragma unroll
        for (int j = 0; j < 4; ++j) {
            const float w = bf16_lo(p[j]);
            a0 = fmaf(bf16_lo(r[j]), w, a0);
            a1 = fmaf(bf16_hi(r[j]), w, a1);
        }
    }
    for (; i < end; ++i) {
        const unsigned p = pairs[i];
        const unsigned r = vrepr16[(size_t)(p >> 16) * 64 + l];
        const float w = bf16_lo(p);
        a0 = fmaf(bf16_lo(r), w, a0); a1 = fmaf(bf16_hi(r), w, a1);
    }
    const unsigned pk = (unsigned)f2bf(a0) | ((unsigned)f2bf(a1) << 16);
    __builtin_nontemporal_store(pk, accu + (size_t)v * 128 + l);
}

// ---------------------------------------------------------------------------
// gemm via MFMA 16x16x32 bf16. A-tile read pre-packed bf16: 256 B/row,
// no f32->bf16 pack phase. In-place safe: block reads exactly the acc16
// region of the rows it overwrites.
// ---------------------------------------------------------------------------
__global__ __launch_bounds__(256) void gemm_mfma_kernel(
    const unsigned int* accu, const unsigned int* __restrict__ bfrag,
    const float* __restrict__ loc_b, const float* __restrict__ std_b,
    float* out)
{
    __shared__ unsigned short tile[16][136];   // bf16, padded
    const int t = threadIdx.x;
    const int row0 = blockIdx.x * 16;
    const int l = t & 63, w = t >> 6;

    short8 bfr[4][4];
#pragma unroll
    for (int ct = 0; ct < 4; ++ct)
#pragma unroll
        for (int ks = 0; ks < 4; ++ks)
            bfr[ct][ks] = *reinterpret_cast<const short8*>(
                bfrag + ((((w * 4 + ct) * 4 + ks) * 64 + l) << 2));

    {
        const uint4 av = *reinterpret_cast<const uint4*>(
            accu + (size_t)(row0 + (t >> 4)) * 128 + (t & 15) * 4);
        *reinterpret_cast<uint4*>(&tile[t >> 4][(t & 15) * 8]) = av;
    }
    __syncthreads();

    const int m = l & 15, q = l >> 4;
    v4f accv[4];
#pragma unroll
    for (int ct = 0; ct < 4; ++ct) accv[ct] = (v4f){0.0f, 0.0f, 0.0f, 0.0f};

#pragma unroll
    for (int ks = 0; ks < 4; ++ks) {
        const short8 a = *reinterpret_cast<const short8*>(&tile[m][ks * 32 + q * 8]);
#pragma unroll
        for (int ct = 0; ct < 4; ++ct)
            accv[ct] = __builtin_amdgcn_mfma_f32_16x16x32_bf16(
                a, bfr[ct][ks], accv[ct], 0, 0, 0);
    }

#pragma unroll
    for (int ct = 0; ct < 4; ++ct) {
        const int colg = (w * 4 + ct) * 16 + m;
        const int h = colg >> 7, c = colg & 127;
        const float bias = (h ? std_b : loc_b)[c];
        float* dst = out + (h ? (size_t)VNUM * OUTF : (size_t)0);
#pragma unroll
        for (int reg = 0; reg < 4; ++reg) {
            const int row = row0 + q * 4 + reg;
            float x = accv[ct][reg] + bias;
            if (h) x = fmaxf(x, 0.0f) + log1pf(expf(-fabsf(x))) + EPSF;
            dst[(size_t)row * OUTF + c] = x;
        }
    }
}

// Fallback gemm (no workspace): f32 vector path, unpacks bf16 acc.
__global__ __launch_bounds__(256) void gemm_fallback_kernel(
    const unsigned int* accu,
    const float* __restrict__ loc_w, const float* __restrict__ loc_b,
    const float* __restrict__ std_w, const float* __restrict__ std_b,
    float* out)
{
    __shared__ float tile[16][OUTF];
    const int t = threadIdx.x;
    const int row0 = blockIdx.x * 16;
    {
        const uint4 av = *reinterpret_cast<const uint4*>(
            accu + (size_t)(row0 + (t >> 4)) * 128 + (t & 15) * 4);
        float* dst = &tile[t >> 4][(t & 15) * 8];
        dst[0] = bf16_lo(av.x); dst[1] = bf16_hi(av.x);
        dst[2] = bf16_lo(av.y); dst[3] = bf16_hi(av.y);
        dst[4] = bf16_lo(av.z); dst[5] = bf16_hi(av.z);
        dst[6] = bf16_lo(av.w); dst[7] = bf16_hi(av.w);
    }
    __syncthreads();
    const int is_std = t >> 7;
    const int c = t & 127;
    const float* w = (is_std ? std_w : loc_w) + (size_t)c * OUTF;
    const float bias = is_std ? std_b[c] : loc_b[c];
    float accv[16];
#pragma unroll
    for (int r = 0; r < 16; ++r) accv[r] = 0.0f;
    for (int k = 0; k < OUTF; k += 4) {
        const float4 wv = *reinterpret_cast<const float4*>(w + k);
#pragma unroll
        for (int r = 0; r < 16; ++r) {
            const float4 pv = *reinterpret_cast<const float4*>(&tile[r][k]);
            float a = accv[r];
            a = fmaf(pv.x, wv.x, a); a = fmaf(pv.y, wv.y, a);
            a = fmaf(pv.z, wv.z, a); a = fmaf(pv.w, wv.w, a);
            accv[r] = a;
        }
    }
    float* dst_base = out + (is_std ? (size_t)VNUM * OUTF : (size_t)0);
#pragma unroll
    for (int r = 0; r < 16; ++r) {
        const float x = accv[r] + bias;
        dst_base[(size_t)(row0 + r) * OUTF + c] =
            is_std ? (fmaxf(x, 0.0f) + log1pf(expf(-fabsf(x))) + EPSF) : x;
    }
}

extern "C" void kernel_launch(void* const* d_in, const int* in_sizes, int n_in,
                              void* d_out, int out_size, void* d_ws, size_t ws_size,
                              hipStream_t stream) {
    const int*   sidx  = (const int*)  d_in[0];
    const int*   tidx  = (const int*)  d_in[1];
    const float* enorm = (const float*)d_in[2];
    const float* esgn  = (const float*)d_in[3];
    const float* vrepr = (const float*)d_in[4];
    const float* loc_w = (const float*)d_in[5];
    const float* loc_b = (const float*)d_in[6];
    const float* std_w = (const float*)d_in[7];
    const float* std_b = (const float*)d_in[8];

    float* out = (float*)d_out;

    // coarse8: 49 fixed-stride segments (49*36864*8B = 14.45 MB) in the loc
    // half of out (25.6 MB); dead after scatter_fine. Then the loc half holds
    // acc16 (packed bf16, identity-strided: row v -> uints [v*128, v*128+64)).
    uint2* coarse8 = (uint2*)out;
    unsigned int* accu = (unsigned int*)out;

    // std-half scratch layout (~5.05M of 6.4M words):
    //   pairs 1.6M | vrepr16 3.2M | offs 50001 | ccursor 49 | hcnt 196*1024
    unsigned int* sbase   = (unsigned int*)(out + (size_t)VNUM * OUTF);
    unsigned int* pairs   = sbase;
    unsigned int* vrepr16 = sbase + NEDGE;
    int* offs    = (int*)(sbase + NEDGE + (size_t)VNUM * 64);
    int* ccursor = offs + VNUM + 1;
    int* hcnt    = ccursor + NCB;

    const bool use_ws = ws_size >= 16384 * sizeof(unsigned int);  // 64 KB
    unsigned int* bfrag = use_ws ? (unsigned int*)d_ws : nullptr;

    const int prep_blocks = CONV_BLOCKS + 1 + (use_ws ? BFRAG_BLOCKS : 0);
    prep_kernel        <<<prep_blocks, 256, 0, stream>>>(vrepr, vrepr16, ccursor,
                                                         offs, loc_w, std_w, bfrag);
    coarse_kernel      <<<COARSE_BLOCKS, 256, 0, stream>>>(sidx, tidx, enorm, esgn,
                                                           ccursor, coarse8);
    hist_kernel        <<<FINE_BLOCKS, 1024, 0, stream>>>(coarse8, ccursor, hcnt);
    scatter_fine_kernel<<<FINE_BLOCKS, 1024, 0, stream>>>(coarse8, ccursor, hcnt,
                                                          offs, pairs);
    aggregate_kernel   <<<VNUM / 4, 256, 0, stream>>>(offs, pairs, vrepr16, accu);

    if (use_ws) {
        gemm_mfma_kernel<<<VNUM / 16, 256, 0, stream>>>(accu, bfrag, loc_b, std_b, out);
    } else {
        gemm_fallback_kernel<<<VNUM / 16, 256, 0, stream>>>(accu, loc_w, loc_b,
                                                            std_w, std_b, out);
    }
}

// Round 21
// 225.908 us; speedup vs baseline: 6.8058x; 1.0118x over previous
//
#include <hip/hip_runtime.h>
#include <math.h>

#define VNUM 50000
#define OUTF 128
#define NEDGE 1600000
#define EPSF 1e-7f

#define BFRAG_BLOCKS 64     // 16384 uint pairs / 256

#define CHUNK 2048          // edges per coarse block
#define NCB 49              // coarse bins: tidx>>10 (1024 vertices/bin)
#define COARSE_BLOCKS 782   // ceil(NEDGE/CHUNK)
#define BSTRIDE 36864       // fixed segment stride; mean 32768 + 23 sigma
#define NSUB 4              // sub-blocks per bin (R8: 8 = +6.5us; R10 coop = +35us; R15 LDS-fuse = +1300us)
#define FINE_BLOCKS (NCB * NSUB)   // 196
#define CONV_BLOCKS 782     // conversion blocks @1024 thr: 800000 thr x 8 floats

typedef __attribute__((ext_vector_type(8))) short short8;
typedef __attribute__((ext_vector_type(4))) float v4f;

// ---------------------------------------------------------------------------
// bf16 helpers (RNE)
// ---------------------------------------------------------------------------
__device__ __forceinline__ unsigned short f2bf(float f) {
    union { float f; unsigned int u; } c; c.f = f;
    unsigned int u = c.u;
    return (unsigned short)((u + 0x7FFFu + ((u >> 16) & 1u)) >> 16);
}
__device__ __forceinline__ float bf16_lo(unsigned int p) {
    union { unsigned int u; float f; } c; c.u = p << 16; return c.f;
}
__device__ __forceinline__ float bf16_hi(unsigned int p) {
    union { unsigned int u; float f; } c; c.u = p & 0xFFFF0000u; return c.f;
}

__device__ __forceinline__ int wave_incl_scan(int v, int lane) {
#pragma unroll
    for (int off = 1; off < 64; off <<= 1) {
        const int o = __shfl_up(v, off, 64);
        if (lane >= off) v += o;
    }
    return v;
}

// ---------------------------------------------------------------------------
// prep (R18: tiny — conversion moved into hist launch): block 0 = ccursor
// init + offs[VNUM]; blocks 1..64 = MFMA B-fragment build.
// ---------------------------------------------------------------------------
__global__ __launch_bounds__(256) void prep_kernel(
    int* __restrict__ ccursor, int* __restrict__ offs,
    const float* __restrict__ loc_w, const float* __restrict__ std_w,
    unsigned int* bfrag)
{
    const int b = blockIdx.x, tid = threadIdx.x;
    if (b == 0) {
        if (tid < NCB) ccursor[tid] = tid * BSTRIDE;
        if (tid == 63) offs[VNUM] = NEDGE;
    } else {
        const int p = (b - 1) * 256 + tid; // 0..16383
        const int j2 = p & 3, lq = (p >> 2) & 63, ks = (p >> 8) & 3, ct = p >> 10;
        const int k = ks * 32 + (lq >> 4) * 8 + j2 * 2;
        const int n = ct * 16 + (lq & 15);
        const float* wsrc = (n >> 7) ? std_w : loc_w;
        const int c = n & 127;
        bfrag[p] = (unsigned)f2bf(wsrc[c * 128 + k]) |
                   ((unsigned)f2bf(wsrc[c * 128 + k + 1]) << 16);
    }
}

// ---------------------------------------------------------------------------
// coarse: partition edges into 49 fixed-stride bin segments via LDS staging
// + bulk-reserved contiguous runs. R18: 6-byte records — c8m = uint
// {sidx<<16|bf16(w)}, c8v = ushort tidx (tidx<50000<65536). Writes
// 10.8MB instead of 14.45MB; LDS staging 12KB instead of 16KB.
// ---------------------------------------------------------------------------
__global__ __launch_bounds__(256) void coarse_kernel(
    const int* __restrict__ sidx, const int* __restrict__ tidx,
    const float* __restrict__ enorm, const float* __restrict__ esgn,
    int* __restrict__ ccursor,
    unsigned int* __restrict__ c8m, unsigned short* __restrict__ c8v)
{
    __shared__ unsigned int   lrecm[CHUNK];   // 8 KB
    __shared__ unsigned short lrecv[CHUNK];   // 4 KB
    __shared__ int lcnt[4][NCB];
    __shared__ int lbase[4][NCB];
    __shared__ int loffs[NCB];
    __shared__ int grun[NCB];

    const int tid = threadIdx.x, lane = tid & 63, wv = tid >> 6;
    const int base = blockIdx.x * CHUNK;
    const int n = min(CHUNK, NEDGE - base);

    for (int i = tid; i < 4 * NCB; i += 256) (&lcnt[0][0])[i] = 0;
    __syncthreads();

    unsigned int rm[8];
    unsigned short rv[8];
#pragma unroll
    for (int j = 0; j < 8; ++j) {
        const int e = base + j * 256 + tid;
        if (e < NEDGE) {
            const int t = tidx[e];
            const float w = esgn[e] * enorm[e];
            rm[j] = ((unsigned)sidx[e] << 16) | (unsigned)f2bf(w);
            rv[j] = (unsigned short)t;
            atomicAdd(&lcnt[wv][t >> 10], 1);
        }
    }
    __syncthreads();

    if (tid < 64) {
        int c0 = 0, c1 = 0, c2 = 0, c3 = 0, tot = 0;
        if (lane < NCB) {
            c0 = lcnt[0][lane]; c1 = lcnt[1][lane];
            c2 = lcnt[2][lane]; c3 = lcnt[3][lane];
            tot = c0 + c1 + c2 + c3;
        }
        const int inc = wave_incl_scan(tot, lane);
        const int ex = inc - tot;
        if (lane < NCB) {
            loffs[lane]    = ex;
            lbase[0][lane] = ex;
            lbase[1][lane] = ex + c0;
            lbase[2][lane] = ex + c0 + c1;
            lbase[3][lane] = ex + c0 + c1 + c2;
            grun[lane] = atomicAdd(&ccursor[lane], tot);
        }
    }
    __syncthreads();

#pragma unroll
    for (int j = 0; j < 8; ++j) {
        const int e = base + j * 256 + tid;
        if (e < NEDGE) {
            const int cb = (int)rv[j] >> 10;
            const int pos = atomicAdd(&lbase[wv][cb], 1);
            lrecm[pos] = rm[j];
            lrecv[pos] = rv[j];
        }
    }
    __syncthreads();

    for (int i = tid; i < n; i += 256) {
        const unsigned int   m = lrecm[i];
        const unsigned short v = lrecv[i];
        const int cb = (int)v >> 10;
        const int dst = grun[cb] + (i - loffs[cb]);
        c8m[dst] = m;
        c8v[dst] = v;
    }
}

// ---------------------------------------------------------------------------
// hist_conv (R18): blocks 0..195 = fine hist (reads ONLY the 2-byte c8v
// stream — 3.2MB instead of 12.8MB); blocks 196..977 = vrepr f32->bf16x2
// conversion (independent of coarse; hidden under hist's CU-idle slots).
// ---------------------------------------------------------------------------
__global__ __launch_bounds__(1024) void hist_conv_kernel(
    const unsigned short* __restrict__ c8v, const int* __restrict__ ccursor,
    int* __restrict__ hcnt,
    const float* __restrict__ vrepr, unsigned int* __restrict__ vrepr16)
{
    __shared__ int cnt[1024];
    const int b = blockIdx.x, tid = threadIdx.x;
    if (b < FINE_BLOCKS) {
        const int bin = b >> 2, s = b & 3;
        const int bs = bin * BSTRIDE;
        const int len = ccursor[bin] - bs;
        const int qs = bs + ((len * s) >> 2);
        const int qe = bs + ((len * (s + 1)) >> 2);
        cnt[tid] = 0;
        __syncthreads();
        for (int i = qs + tid; i < qe; i += 1024)
            atomicAdd(&cnt[c8v[i] & 1023], 1);
        __syncthreads();
        hcnt[b * 1024 + tid] = cnt[tid];
    } else {
        const int gid = (b - FINE_BLOCKS) * 1024 + tid;   // 0..800767
        if (gid < (VNUM * OUTF) / 8) {
            const float4 v0 = *reinterpret_cast<const float4*>(vrepr + (size_t)gid * 8);
            const float4 v1 = *reinterpret_cast<const float4*>(vrepr + (size_t)gid * 8 + 4);
            uint4 pk;
            pk.x = (unsigned)f2bf(v0.x) | ((unsigned)f2bf(v0.y) << 16);
            pk.y = (unsigned)f2bf(v0.z) | ((unsigned)f2bf(v0.w) << 16);
            pk.z = (unsigned)f2bf(v1.x) | ((unsigned)f2bf(v1.y) << 16);
            pk.w = (unsigned)f2bf(v1.z) | ((unsigned)f2bf(v1.w) << 16);
            *reinterpret_cast<uint4*>(vrepr16 + (size_t)gid * 4) = pk;
        }
    }
}

// ---------------------------------------------------------------------------
// scatter_fine: wave 0 recomputes the 49-bin packed prefix from ccursor,
// then bin-wide scan from the 4 hcnt slices, seeds LDS cursors at
// offs[v] + prefix(earlier sub-blocks), ranks + scatters its quarter.
// R18: reads c8m (4B) + c8v (2B) = 9.6MB instead of 12.8MB.
// ---------------------------------------------------------------------------
__global__ __launch_bounds__(1024) void scatter_fine_kernel(
    const unsigned int* __restrict__ c8m, const unsigned short* __restrict__ c8v,
    const int* __restrict__ ccursor, const int* __restrict__ hcnt,
    int* __restrict__ offs, unsigned int* __restrict__ pairs)
{
    __shared__ int cur[1024];
    __shared__ int wsum[16];
    __shared__ int sh_s0;
    const int tid = threadIdx.x, lane = tid & 63, wv = tid >> 6;
    const int bin = blockIdx.x >> 2, s = blockIdx.x & 3;
    const int bs = bin * BSTRIDE;

    if (tid < 64) {
        const int lenl = (tid < NCB) ? (ccursor[tid] - tid * BSTRIDE) : 0;
        const int incc = wave_incl_scan(lenl, tid);
        if (tid == bin) sh_s0 = incc - lenl;   // packed exclusive prefix
    }

    const int len = ccursor[bin] - bs;
    const int qs = bs + ((len * s) >> 2);
    const int qe = bs + ((len * (s + 1)) >> 2);

    const int c0 = hcnt[(bin * 4 + 0) * 1024 + tid];
    const int c1 = hcnt[(bin * 4 + 1) * 1024 + tid];
    const int c2 = hcnt[(bin * 4 + 2) * 1024 + tid];
    const int c3 = hcnt[(bin * 4 + 3) * 1024 + tid];
    const int tot = c0 + c1 + c2 + c3;
    const int pre = (s > 0 ? c0 : 0) + (s > 1 ? c1 : 0) + (s > 2 ? c2 : 0);

    const int inc = wave_incl_scan(tot, lane);
    if (lane == 63) wsum[wv] = inc;
    __syncthreads();
    if (tid == 0) {
        int run = 0;
        for (int i = 0; i < 16; ++i) { const int t = wsum[i]; wsum[i] = run; run += t; }
    }
    __syncthreads();
    const int ex = sh_s0 + wsum[wv] + inc - tot;   // global offs for vertex gv
    const int gv = (bin << 10) + tid;
    if (s == 0 && gv < VNUM) offs[gv] = ex;
    cur[tid] = ex + pre;
    __syncthreads();

    for (int i = qs + tid; i < qe; i += 1024) {
        const unsigned short v = c8v[i];
        const int pos = atomicAdd(&cur[(int)v & 1023], 1);
        pairs[pos] = c8m[i];
    }
}

// ---------------------------------------------------------------------------
// aggregate (R11-proven, unchanged): one wave per vertex, lane covers cols
// (2l, 2l+1). 256 B coalesced bf16-row gathers, unroll-12, CACHED pairs
// loads + nontemporal PACKED-BF16 store (WRITE 25->12.5MB).
// ---------------------------------------------------------------------------
__global__ __launch_bounds__(256) void aggregate_kernel(
    const int* __restrict__ offs, const unsigned int* __restrict__ pairs,
    const unsigned int* __restrict__ vrepr16, unsigned int* __restrict__ accu)
{
    const int v = blockIdx.x * 4 + (threadIdx.x >> 6);
    const int l = threadIdx.x & 63;
    int i = offs[v];
    const int end = offs[v + 1];

    float a0 = 0.0f, a1 = 0.0f;
    for (; i + 12 <= end; i += 12) {
        unsigned p[12], r[12];
#pragma unroll
        for (int j = 0; j < 12; ++j) p[j] = pairs[i + j];
#pragma unroll
        for (int j = 0; j < 12; ++j) r[j] = vrepr16[(size_t)(p[j] >> 16) * 64 + l];
#pragma unroll
        for (int j = 0; j < 12; ++j) {
            const float w = bf16_lo(p[j]);
            a0 = fmaf(bf16_lo(r[j]), w, a0);
            a1 = fmaf(bf16_hi(r[j]), w, a1);
        }
    }
    for (; i + 4 <= end; i += 4) {
        unsigned p[4], r[4];
#pragma unroll
        for (int j = 0; j < 4; ++j) p[j] = pairs[i + j];
#pragma unroll
        for (int j = 0; j < 4; ++j) r[j] = vrepr16[(size_t)(p[j] >> 16) * 64 + l];
#pragma unroll
        for (int j = 0; j < 4; ++j) {
            const float w = bf16_lo(p[j]);
            a0 = fmaf(bf16_lo(r[j]), w, a0);
            a1 = fmaf(bf16_hi(r[j]), w, a1);
        }
    }
    for (; i < end; ++i) {
        const unsigned p = pairs[i];
        const unsigned r = vrepr16[(size_t)(p >> 16) * 64 + l];
        const float w = bf16_lo(p);
        a0 = fmaf(bf16_lo(r), w, a0); a1 = fmaf(bf16_hi(r), w, a1);
    }
    const unsigned pk = (unsigned)f2bf(a0) | ((unsigned)f2bf(a1) << 16);
    __builtin_nontemporal_store(pk, accu + (size_t)v * 128 + l);
}

// ---------------------------------------------------------------------------
// gemm via MFMA 16x16x32 bf16 (unchanged). A-tile read pre-packed bf16:
// 256 B/row. In-place safe: block reads exactly the acc16 region of the
// rows it overwrites.
// ---------------------------------------------------------------------------
__global__ __launch_bounds__(256) void gemm_mfma_kernel(
    const unsigned int* accu, const unsigned int* __restrict__ bfrag,
    const float* __restrict__ loc_b, const float* __restrict__ std_b,
    float* out)
{
    __shared__ unsigned short tile[16][136];   // bf16, padded
    const int t = threadIdx.x;
    const int row0 = blockIdx.x * 16;
    const int l = t & 63, w = t >> 6;

    short8 bfr[4][4];
#pragma unroll
    for (int ct = 0; ct < 4; ++ct)
#pragma unroll
        for (int ks = 0; ks < 4; ++ks)
            bfr[ct][ks] = *reinterpret_cast<const short8*>(
                bfrag + ((((w * 4 + ct) * 4 + ks) * 64 + l) << 2));

    {
        const uint4 av = *reinterpret_cast<const uint4*>(
            accu + (size_t)(row0 + (t >> 4)) * 128 + (t & 15) * 4);
        *reinterpret_cast<uint4*>(&tile[t >> 4][(t & 15) * 8]) = av;
    }
    __syncthreads();

    const int m = l & 15, q = l >> 4;
    v4f accv[4];
#pragma unroll
    for (int ct = 0; ct < 4; ++ct) accv[ct] = (v4f){0.0f, 0.0f, 0.0f, 0.0f};

#pragma unroll
    for (int ks = 0; ks < 4; ++ks) {
        const short8 a = *reinterpret_cast<const short8*>(&tile[m][ks * 32 + q * 8]);
#pragma unroll
        for (int ct = 0; ct < 4; ++ct)
            accv[ct] = __builtin_amdgcn_mfma_f32_16x16x32_bf16(
                a, bfr[ct][ks], accv[ct], 0, 0, 0);
    }

#pragma unroll
    for (int ct = 0; ct < 4; ++ct) {
        const int colg = (w * 4 + ct) * 16 + m;
        const int h = colg >> 7, c = colg & 127;
        const float bias = (h ? std_b : loc_b)[c];
        float* dst = out + (h ? (size_t)VNUM * OUTF : (size_t)0);
#pragma unroll
        for (int reg = 0; reg < 4; ++reg) {
            const int row = row0 + q * 4 + reg;
            float x = accv[ct][reg] + bias;
            if (h) x = fmaxf(x, 0.0f) + log1pf(expf(-fabsf(x))) + EPSF;
            dst[(size_t)row * OUTF + c] = x;
        }
    }
}

// Fallback gemm (no workspace): f32 vector path, unpacks bf16 acc.
__global__ __launch_bounds__(256) void gemm_fallback_kernel(
    const unsigned int* accu,
    const float* __restrict__ loc_w, const float* __restrict__ loc_b,
    const float* __restrict__ std_w, const float* __restrict__ std_b,
    float* out)
{
    __shared__ float tile[16][OUTF];
    const int t = threadIdx.x;
    const int row0 = blockIdx.x * 16;
    {
        const uint4 av = *reinterpret_cast<const uint4*>(
            accu + (size_t)(row0 + (t >> 4)) * 128 + (t & 15) * 4);
        float* dst = &tile[t >> 4][(t & 15) * 8];
        dst[0] = bf16_lo(av.x); dst[1] = bf16_hi(av.x);
        dst[2] = bf16_lo(av.y); dst[3] = bf16_hi(av.y);
        dst[4] = bf16_lo(av.z); dst[5] = bf16_hi(av.z);
        dst[6] = bf16_lo(av.w); dst[7] = bf16_hi(av.w);
    }
    __syncthreads();
    const int is_std = t >> 7;
    const int c = t & 127;
    const float* w = (is_std ? std_w : loc_w) + (size_t)c * OUTF;
    const float bias = is_std ? std_b[c] : loc_b[c];
    float accv[16];
#pragma unroll
    for (int r = 0; r < 16; ++r) accv[r] = 0.0f;
    for (int k = 0; k < OUTF; k += 4) {
        const float4 wv = *reinterpret_cast<const float4*>(w + k);
#pragma unroll
        for (int r = 0; r < 16; ++r) {
            const float4 pv = *reinterpret_cast<const float4*>(&tile[r][k]);
            float a = accv[r];
            a = fmaf(pv.x, wv.x, a); a = fmaf(pv.y, wv.y, a);
            a = fmaf(pv.z, wv.z, a); a = fmaf(pv.w, wv.w, a);
            accv[r] = a;
        }
    }
    float* dst_base = out + (is_std ? (size_t)VNUM * OUTF : (size_t)0);
#pragma unroll
    for (int r = 0; r < 16; ++r) {
        const float x = accv[r] + bias;
        dst_base[(size_t)(row0 + r) * OUTF + c] =
            is_std ? (fmaxf(x, 0.0f) + log1pf(expf(-fabsf(x))) + EPSF) : x;
    }
}

extern "C" void kernel_launch(void* const* d_in, const int* in_sizes, int n_in,
                              void* d_out, int out_size, void* d_ws, size_t ws_size,
                              hipStream_t stream) {
    const int*   sidx  = (const int*)  d_in[0];
    const int*   tidx  = (const int*)  d_in[1];
    const float* enorm = (const float*)d_in[2];
    const float* esgn  = (const float*)d_in[3];
    const float* vrepr = (const float*)d_in[4];
    const float* loc_w = (const float*)d_in[5];
    const float* loc_b = (const float*)d_in[6];
    const float* std_w = (const float*)d_in[7];
    const float* std_b = (const float*)d_in[8];

    float* out = (float*)d_out;

    // Loc half: c8m (1.806M uints, 7.2MB) + c8v (1.806M ushorts, 3.6MB) —
    // dead after scatter_fine. Then loc half holds acc16 (packed bf16,
    // identity-strided: row v -> uints [v*128, v*128+64)).
    unsigned int*   c8m  = (unsigned int*)out;
    unsigned short* c8v  = (unsigned short*)(c8m + (size_t)NCB * BSTRIDE);
    unsigned int*   accu = (unsigned int*)out;

    // std-half scratch layout (~5.05M of 6.4M words):
    //   pairs 1.6M | vrepr16 3.2M | offs 50001 | ccursor 49 | hcnt 196*1024
    unsigned int* sbase   = (unsigned int*)(out + (size_t)VNUM * OUTF);
    unsigned int* pairs   = sbase;
    unsigned int* vrepr16 = sbase + NEDGE;
    int* offs    = (int*)(sbase + NEDGE + (size_t)VNUM * 64);
    int* ccursor = offs + VNUM + 1;
    int* hcnt    = ccursor + NCB;

    const bool use_ws = ws_size >= 16384 * sizeof(unsigned int);  // 64 KB
    unsigned int* bfrag = use_ws ? (unsigned int*)d_ws : nullptr;

    const int prep_blocks = 1 + (use_ws ? BFRAG_BLOCKS : 0);
    prep_kernel        <<<prep_blocks, 256, 0, stream>>>(ccursor, offs,
                                                         loc_w, std_w, bfrag);
    coarse_kernel      <<<COARSE_BLOCKS, 256, 0, stream>>>(sidx, tidx, enorm, esgn,
                                                           ccursor, c8m, c8v);
    hist_conv_kernel   <<<FINE_BLOCKS + CONV_BLOCKS, 1024, 0, stream>>>(
                            c8v, ccursor, hcnt, vrepr, vrepr16);
    scatter_fine_kernel<<<FINE_BLOCKS, 1024, 0, stream>>>(c8m, c8v, ccursor, hcnt,
                                                          offs, pairs);
    aggregate_kernel   <<<VNUM / 4, 256, 0, stream>>>(offs, pairs, vrepr16, accu);

    if (use_ws) {
        gemm_mfma_kernel<<<VNUM / 16, 256, 0, stream>>>(accu, bfrag, loc_b, std_b, out);
    } else {
        gemm_fallback_kernel<<<VNUM / 16, 256, 0, stream>>>(accu, loc_w, loc_b,
                                                            std_w, std_b, out);
    }
}